// Round 7
// baseline (335.519 us; speedup 1.0000x reference)
//
#include <hip/hip_runtime.h>

// ---------------------------------------------------------------------------
// PEPS 4x5, D=4, P=2, depth-5 gate sweeps, 64-point gather.
// psi kept in COLUMN-major qubit order: qubit (i,j) at bit (19 - 4*j - i).
// 3 phases/iteration:
//   P2' k_ha    : H rows 2,3                (16KB slab, grid 256)  [proven]
//   P1' k_r01c01: H rows 0,1 + V cols 0,1   (64KB slab, grid 64)   [new]
//   P3' k_vall  : V cols 2,3,4 (+gather)    (16KB slab, grid 256)
// ---------------------------------------------------------------------------

#define PAD(i) ((i) + (((i) >> 4) << 2))   // +4 floats per 16 -> LDS bank spread
#define PIDX(i,j,p,u,d,l,r) (((((((i)*5+(j))*2+(p))*4+(u))*4+(d))*4+(l))*4+(r))

// workspace float offsets
static constexpr int COL0  = 0;                    // [16][256]
static constexpr int COL1  = 4096;                 // [16][256][256]
static constexpr int COL2  = COL1 + 1048576;
static constexpr int COL3  = COL2 + 1048576;
static constexpr int COL4  = COL3 + 1048576;       // [16][256]
static constexpr int M01TO = COL4 + 4096;          // [c01=256][R2=256]
static constexpr int M34TO = M01TO + 65536;        // [L3=256][c34=256]
static constexpr int T12TO = M34TO + 65536;        // [c2=16][c01=256][R3=256]
static constexpr int PSIO  = T12TO + 1048576;      // [2^20]

// --------------------------- column tensors --------------------------------
__global__ __launch_bounds__(256) void k_build_cols(const float* __restrict__ peps,
                                                    float* __restrict__ ws) {
  __shared__ float p01[4096], p23[4096];
  int bid = blockIdx.x, t = threadIdx.x;
  if (bid < 384) {
    int col = 1 + (bid >> 7);
    int part = bid & 127;
#pragma unroll
    for (int k = 0; k < 16; ++k) {
      int e = k * 256 + t;
      int r12 = e & 15, l12 = (e >> 4) & 15, d2 = (e >> 8) & 3, p = e >> 10;
      int l1 = l12 >> 2, l2 = l12 & 3, r1 = r12 >> 2, r2 = r12 & 3;
      float s01 = 0.f, s23 = 0.f;
#pragma unroll
      for (int d = 0; d < 4; ++d) {
        s01 += peps[PIDX(0, col, (p >> 1), 0, d, l1, r1)] *
               peps[PIDX(1, col, (p & 1), d, d2, l2, r2)];
        s23 += peps[PIDX(2, col, (p >> 1), d2, d, l1, r1)] *
               peps[PIDX(3, col, (p & 1), d, 0, l2, r2)];
      }
      p01[e] = s01;
      p23[e] = s23;
    }
    __syncthreads();
    const int coloffs[3] = {COL1, COL2, COL3};
    float* out = ws + coloffs[col - 1];
#pragma unroll
    for (int k = 0; k < 8; ++k) {
      int eq = part * 8192 + (k * 256 + t) * 4;
      int r34b = eq & 15;
      int r12 = (eq >> 4) & 15, l34 = (eq >> 8) & 15, l12 = (eq >> 12) & 15;
      int p = eq >> 16;
      int pa = p >> 2, pb = p & 3;
      float4 acc = {0.f, 0.f, 0.f, 0.f};
#pragma unroll
      for (int d2 = 0; d2 < 4; ++d2) {
        float a01 = p01[((((pa * 4 + d2) << 4) | l12) << 4) | r12];
        const float4 b4 =
            *(const float4*)&p23[((((pb * 4 + d2) << 4) | l34) << 4) | r34b];
        acc.x += a01 * b4.x;
        acc.y += a01 * b4.y;
        acc.z += a01 * b4.z;
        acc.w += a01 * b4.w;
      }
      *(float4*)&out[eq] = acc;
    }
  } else {
    int col = (bid == 384) ? 0 : 4;
    const int lsh = (col == 0) ? 0 : 2;
    const int rsh = (col == 4) ? 0 : 2;
    const int ldim = 1 << lsh, rdim = 1 << rsh;
    const int LLB = 2 * lsh, RRB = 2 * rsh;
    const int LL = 1 << LLB, RR = 1 << RRB;
    int n12 = (LL * RR) << 4;
    for (int e = t; e < n12; e += 256) {
      int r12 = e & (RR - 1);
      int l12 = (e >> RRB) & (LL - 1);
      int d2 = (e >> (RRB + LLB)) & 3;
      int p = e >> (RRB + LLB + 2);
      int l1 = l12 >> lsh, l2 = l12 & (ldim - 1);
      int r1 = r12 >> rsh, r2 = r12 & (rdim - 1);
      float s01 = 0.f, s23 = 0.f;
      for (int d = 0; d < 4; ++d) {
        s01 += peps[PIDX(0, col, (p >> 1), 0, d, l1, r1)] *
               peps[PIDX(1, col, (p & 1), d, d2, l2, r2)];
        s23 += peps[PIDX(2, col, (p >> 1), d2, d, l1, r1)] *
               peps[PIDX(3, col, (p & 1), d, 0, l2, r2)];
      }
      p01[e] = s01;
      p23[e] = s23;
    }
    __syncthreads();
    const int LB = 2 * LLB, RB = 2 * RRB;
    int total = 16 << (LB + RB);  // 4096
    float* out = ws + ((col == 0) ? COL0 : COL4);
    for (int e = t; e < total; e += 256) {
      int r = e & ((1 << RB) - 1);
      int l = (e >> RB) & ((1 << LB) - 1);
      int p = e >> (RB + LB);
      int r34 = r & (RR - 1), r12 = r >> RRB;
      int l34 = l & (LL - 1), l12 = l >> LLB;
      int pa = p >> 2, pb = p & 3;
      float s = 0.f;
      for (int d2 = 0; d2 < 4; ++d2) {
        s += p01[((((pa * 4 + d2) << LLB) | l12) << RRB) | r12] *
             p23[((((pb * 4 + d2) << LLB) | l34) << RRB) | r34];
      }
      out[e] = s;
    }
  }
}

// ------------------- M01 / M34T (edge-pair contractions) -------------------
__global__ __launch_bounds__(256) void k_small(const float* __restrict__ ws,
                                               float* __restrict__ m01,
                                               float* __restrict__ m34t) {
  __shared__ float c3buf[4112], c4buf[4112];
  int t = threadIdx.x;
  if (blockIdx.x < 64) {
    int c1 = blockIdx.x >> 2, q = blockIdx.x & 3;
    int r2l = t & 63, c0g = t >> 6;  // wave-uniform c0 group (4 c0 each)
    int R2 = q * 64 + r2l;
    const float* col0 = ws + COL0;
    const float* col1 = ws + COL1;
    float a0 = 0.f, a1 = 0.f, a2 = 0.f, a3 = 0.f;
    for (int R1 = 0; R1 < 256; ++R1) {
      float bv = col1[(c1 * 256 + R1) * 256 + R2];  // coalesced
      a0 += col0[(c0g * 4 + 0) * 256 + R1] * bv;    // uniform -> s_load
      a1 += col0[(c0g * 4 + 1) * 256 + R1] * bv;
      a2 += col0[(c0g * 4 + 2) * 256 + R1] * bv;
      a3 += col0[(c0g * 4 + 3) * 256 + R1] * bv;
    }
    m01[((c0g * 4 + 0) * 16 + c1) * 256 + R2] = a0;  // coalesced
    m01[((c0g * 4 + 1) * 16 + c1) * 256 + R2] = a1;
    m01[((c0g * 4 + 2) * 16 + c1) * 256 + R2] = a2;
    m01[((c0g * 4 + 3) * 16 + c1) * 256 + R2] = a3;
  } else {
    int L3 = blockIdx.x - 64;  // 0..255
    const float* col3 = ws + COL3;
    const float* col4 = ws + COL4;
    for (int e = t; e < 4096; e += 256) {
      c4buf[(e >> 8) * 257 + (e & 255)] = col4[e];
      c3buf[(e >> 8) * 257 + (e & 255)] =
          col3[(e >> 8) * 65536 + L3 * 256 + (e & 255)];
    }
    __syncthreads();
    int c3 = t >> 4, c4 = t & 15;
    float acc = 0.f;
    for (int B = 0; B < 256; ++B)
      acc += c3buf[c3 * 257 + B] * c4buf[c4 * 257 + B];
    m34t[L3 * 256 + t] = acc;
  }
}

// ---------------- T012[c2][c01][R3] = M01 x Col2 ---------------------------
__global__ __launch_bounds__(256) void k_t012(const float* __restrict__ m01,
                                              const float* __restrict__ col2,
                                              float* __restrict__ t012) {
  __shared__ float A[4096];  // [i=16][R2=256]
  int t = threadIdx.x;       // R3
  int c2 = blockIdx.x & 15, tg = blockIdx.x >> 4;
#pragma unroll
  for (int k = 0; k < 4; ++k)
    *(float4*)&A[(k * 256 + t) * 4] =
        *(const float4*)&m01[tg * 4096 + (k * 256 + t) * 4];
  __syncthreads();
  float acc[16] = {};
  for (int R2 = 0; R2 < 256; R2 += 4) {
    float b0 = col2[c2 * 65536 + (R2 + 0) * 256 + t];
    float b1 = col2[c2 * 65536 + (R2 + 1) * 256 + t];
    float b2 = col2[c2 * 65536 + (R2 + 2) * 256 + t];
    float b3 = col2[c2 * 65536 + (R2 + 3) * 256 + t];
#pragma unroll
    for (int i = 0; i < 16; ++i) {
      float4 a4 = *(const float4*)&A[i * 256 + R2];  // broadcast b128
      acc[i] += a4.x * b0 + a4.y * b1 + a4.z * b2 + a4.w * b3;
    }
  }
#pragma unroll
  for (int i = 0; i < 16; ++i)
    t012[c2 * 65536 + (tg * 16 + i) * 256 + t] = acc[i];  // coalesced
}

// ---------------- psi = T012 x M34T  (psi[(c01*16+c2)*256 + c34]) ----------
__global__ __launch_bounds__(256) void k_psi0(const float* __restrict__ t012,
                                              const float* __restrict__ m34t,
                                              float* __restrict__ psi) {
  __shared__ float A[4096];  // [i=c2=16][L3=256]
  int t = threadIdx.x;       // c34 (and L3 for staging)
  int tg = blockIdx.x;       // c01
#pragma unroll
  for (int i = 0; i < 16; ++i)
    A[i * 256 + t] = t012[i * 65536 + tg * 256 + t];  // coalesced 1KB chunks
  __syncthreads();
  float acc[16] = {};
  for (int L3 = 0; L3 < 256; L3 += 4) {
    float b0 = m34t[(L3 + 0) * 256 + t];
    float b1 = m34t[(L3 + 1) * 256 + t];
    float b2 = m34t[(L3 + 2) * 256 + t];
    float b3 = m34t[(L3 + 3) * 256 + t];
#pragma unroll
    for (int i = 0; i < 16; ++i) {
      float4 a4 = *(const float4*)&A[i * 256 + L3];  // broadcast b128
      acc[i] += a4.x * b0 + a4.y * b1 + a4.z * b2 + a4.w * b3;
    }
  }
#pragma unroll
  for (int i = 0; i < 16; ++i)
    psi[(tg * 16 + i) * 256 + t] = acc[i];  // coalesced
}

// ---------------- register-level 2-qubit gate ------------------------------
template <int NB, int HI, int LO>
__device__ __forceinline__ void gate2(float* x, const float* __restrict__ g) {
  constexpr int H = 1 << HI, L = 1 << LO, N = 1 << NB;
#pragma unroll
  for (int o = 0; o < N; ++o) {
    if (o & (H | L)) continue;
    float v0 = x[o], v1 = x[o + L], v2 = x[o + H], v3 = x[o + H + L];
    x[o]         = g[0]  * v0 + g[1]  * v1 + g[2]  * v2 + g[3]  * v3;
    x[o + L]     = g[4]  * v0 + g[5]  * v1 + g[6]  * v2 + g[7]  * v3;
    x[o + H]     = g[8]  * v0 + g[9]  * v1 + g[10] * v2 + g[11] * v3;
    x[o + H + L] = g[12] * v0 + g[13] * v1 + g[14] * v2 + g[15] * v3;
  }
}

// H row transform (PAD addressing): 5-bit group, bit4 = leftmost column (j=0)
template <int S4, int S3, int S2, int S1, int S0>
__device__ __forceinline__ void hxf(float* s, const float* __restrict__ g, int b) {
  float x[32];
#pragma unroll
  for (int m = 0; m < 32; ++m) {
    int off = ((m >> 4) & 1) * S4 + ((m >> 3) & 1) * S3 + ((m >> 2) & 1) * S2 +
              ((m >> 1) & 1) * S1 + (m & 1) * S0;
    x[m] = s[PAD(b + off)];
  }
  gate2<5, 4, 3>(x, g);
  gate2<5, 3, 2>(x, g);
  gate2<5, 2, 1>(x, g);
  gate2<5, 1, 0>(x, g);
#pragma unroll
  for (int m = 0; m < 32; ++m) {
    int off = ((m >> 4) & 1) * S4 + ((m >> 3) & 1) * S3 + ((m >> 2) & 1) * S2 +
              ((m >> 1) & 1) * S1 + (m & 1) * S0;
    s[PAD(b + off)] = x[m];
  }
}

// H row transform (raw addressing, for the 64KB kernel)
template <int S4, int S3, int S2, int S1, int S0>
__device__ __forceinline__ void hxfN(float* s, const float* __restrict__ g, int b) {
  float x[32];
#pragma unroll
  for (int m = 0; m < 32; ++m) {
    int off = ((m >> 4) & 1) * S4 + ((m >> 3) & 1) * S3 + ((m >> 2) & 1) * S2 +
              ((m >> 1) & 1) * S1 + (m & 1) * S0;
    x[m] = s[b + off];
  }
  gate2<5, 4, 3>(x, g);
  gate2<5, 3, 2>(x, g);
  gate2<5, 2, 1>(x, g);
  gate2<5, 1, 0>(x, g);
#pragma unroll
  for (int m = 0; m < 32; ++m) {
    int off = ((m >> 4) & 1) * S4 + ((m >> 3) & 1) * S3 + ((m >> 2) & 1) * S2 +
              ((m >> 1) & 1) * S1 + (m & 1) * S0;
    s[b + off] = x[m];
  }
}

// V column transform (PAD): 4-bit nibble, bit3 = row 0
template <int ST>
__device__ __forceinline__ void vxf(float* s, const float* __restrict__ g, int b) {
  float x[16];
#pragma unroll
  for (int m = 0; m < 16; ++m) x[m] = s[PAD(b + m * ST)];
  gate2<4, 3, 2>(x, g);
  gate2<4, 2, 1>(x, g);
  gate2<4, 1, 0>(x, g);
#pragma unroll
  for (int m = 0; m < 16; ++m) s[PAD(b + m * ST)] = x[m];
}

// V column transform (raw)
template <int ST>
__device__ __forceinline__ void vxfN(float* s, const float* __restrict__ g, int b) {
  float x[16];
#pragma unroll
  for (int m = 0; m < 16; ++m) x[m] = s[b + m * ST];
  gate2<4, 3, 2>(x, g);
  gate2<4, 2, 1>(x, g);
  gate2<4, 1, 0>(x, g);
#pragma unroll
  for (int m = 0; m < 16; ++m) s[b + m * ST] = x[m];
}

// P2': H rows 2,3 ; slab bits {17,16,13,12,9,8,5..0} (local: g17->11,g16->10,
// g13->9,g12->8,g9->7,g8->6,g5..0->5..0)
__global__ __launch_bounds__(256) void k_ha(float* __restrict__ psi,
                                            const float* __restrict__ gate) {
  __shared__ float s[5120];
  float g[16];
#pragma unroll
  for (int i = 0; i < 16; ++i) g[i] = gate[i];
  int t = threadIdx.x;  // 256
  int o = blockIdx.x;   // outer bits {19,18,15,14,11,10,7,6}
  int base = ((o >> 6) & 3) * 262144 + ((o >> 4) & 3) * 16384 +
             ((o >> 2) & 3) * 1024 + (o & 3) * 64;
#pragma unroll
  for (int i = 0; i < 4; ++i) {
    int f = (i * 256 + t) * 4;
    int w = f & 63, c = (f >> 6) & 3, b = (f >> 8) & 3, a = (f >> 10) & 3;
    *(float4*)(s + PAD(f)) =
        *(const float4*)(psi + base + a * 65536 + b * 4096 + c * 256 + w);
  }
  __syncthreads();
  if (t < 128) {  // row 2: local bits {11,9,7,5,1}
    int b2 = ((t >> 6) & 1) * 1024 + ((t >> 5) & 1) * 256 + ((t >> 4) & 1) * 64 +
             ((t >> 3) & 1) * 16 + ((t >> 2) & 1) * 8 + ((t >> 1) & 1) * 4 + (t & 1);
    hxf<2048, 512, 128, 32, 2>(s, g, b2);
  }
  __syncthreads();
  if (t < 128) {  // row 3: local bits {10,8,6,4,0}
    int b3 = ((t >> 6) & 1) * 2048 + ((t >> 5) & 1) * 512 + ((t >> 4) & 1) * 128 +
             ((t >> 3) & 1) * 32 + ((t & 7) << 1);
    hxf<1024, 256, 64, 16, 1>(s, g, b3);
  }
  __syncthreads();
#pragma unroll
  for (int i = 0; i < 4; ++i) {
    int f = (i * 256 + t) * 4;
    int w = f & 63, c = (f >> 6) & 3, b = (f >> 8) & 3, a = (f >> 10) & 3;
    *(float4*)(psi + base + a * 65536 + b * 4096 + c * 256 + w) =
        *(const float4*)(s + PAD(f));
  }
}

// P1': H rows 0,1 + V cols 0,1 ; 64KB slab.
// slab bits {19..10, 7,6, 3,2}; local n: n13..4 = g19..10, n3=g7, n2=g6,
// n1=g3, n0=g2.  outer o (6b) = {9,8 | 5,4 | 1,0}.
__global__ __launch_bounds__(256) void k_r01c01(float* __restrict__ psi,
                                                const float* __restrict__ gate) {
  __shared__ float s[16384];  // 64 KB, no pad
  float g[16];
#pragma unroll
  for (int i = 0; i < 16; ++i) g[i] = gate[i];
  int t = threadIdx.x;
  int o = blockIdx.x;  // 0..63
  int obase = ((o >> 4) & 3) * 256 + ((o >> 2) & 3) * 16 + (o & 3);
  // load: psi idx = (n>>4)*1024 + ((n>>2)&3)*64 + (n&3)*4 + obase
#pragma unroll
  for (int k = 0; k < 64; ++k) {
    int n = k * 256 + t;
    s[n] = psi[(n >> 4) * 1024 + ((n >> 2) & 3) * 64 + (n & 3) * 4 + obase];
  }
  __syncthreads();
  // row 0: local bits {13,9,5,3,1}; free {12,11,10,8,7,6,4,2,0}
#pragma unroll
  for (int r = 0; r < 2; ++r) {
    int gg = r * 256 + t;
    int b = ((gg >> 8) & 1) * 4096 + ((gg >> 7) & 1) * 2048 + ((gg >> 6) & 1) * 1024 +
            ((gg >> 5) & 1) * 256 + ((gg >> 4) & 1) * 128 + ((gg >> 3) & 1) * 64 +
            ((gg >> 2) & 1) * 16 + ((gg >> 1) & 1) * 4 + (gg & 1);
    hxfN<8192, 512, 32, 8, 2>(s, g, b);
  }
  __syncthreads();
  // row 1: local bits {12,8,4,2,0}; free {13,11,10,9,7,6,5,3,1}
#pragma unroll
  for (int r = 0; r < 2; ++r) {
    int gg = r * 256 + t;
    int b = ((gg >> 8) & 1) * 8192 + ((gg >> 7) & 1) * 2048 + ((gg >> 6) & 1) * 1024 +
            ((gg >> 5) & 1) * 512 + ((gg >> 4) & 1) * 128 + ((gg >> 3) & 1) * 64 +
            ((gg >> 2) & 1) * 32 + ((gg >> 1) & 1) * 8 + (gg & 1) * 2;
    hxfN<4096, 256, 16, 4, 1>(s, g, b);
  }
  __syncthreads();
  // V col 0: local nibble {13..10}, stride 1024; free {9..0}
#pragma unroll
  for (int r = 0; r < 4; ++r) {
    int gg = r * 256 + t;
    vxfN<1024>(s, g, gg);
  }
  __syncthreads();
  // V col 1: local nibble {9..6}, stride 64; free {13..10, 5..0}
#pragma unroll
  for (int r = 0; r < 4; ++r) {
    int gg = r * 256 + t;
    int b = ((gg >> 6) & 15) * 1024 + (gg & 63);
    vxfN<64>(s, g, b);
  }
  __syncthreads();
  // store
#pragma unroll
  for (int k = 0; k < 64; ++k) {
    int n = k * 256 + t;
    psi[(n >> 4) * 1024 + ((n >> 2) & 3) * 64 + (n & 3) * 4 + obase] = s[n];
  }
}

// P3': V cols 2,3,4 ; slab bits 11..0 (contiguous). GATHER on last iteration.
template <bool GATHER>
__global__ __launch_bounds__(256) void k_vall(float* __restrict__ psi,
                                              const float* __restrict__ gate,
                                              const int* __restrict__ x,
                                              float* __restrict__ out) {
  __shared__ float s[5120];
  float g[16];
#pragma unroll
  for (int i = 0; i < 16; ++i) g[i] = gate[i];
  int t = threadIdx.x;
  int o = blockIdx.x;       // bits 19..12
  int base = o * 4096;
#pragma unroll
  for (int i = 0; i < 4; ++i) {
    int f = (i * 256 + t) * 4;
    *(float4*)(s + PAD(f)) = *(const float4*)(psi + base + f);
  }
  __syncthreads();
  vxf<256>(s, g, t);                             // col 2 (bits 11..8)
  __syncthreads();
  vxf<16>(s, g, ((t >> 4) << 8) | (t & 15));     // col 3 (bits 7..4)
  __syncthreads();
  vxf<1>(s, g, t * 16);                          // col 4 (bits 3..0)
  __syncthreads();
  if (GATHER && t < 64) {
    int idx = 0;
#pragma unroll
    for (int q = 0; q < 20; ++q) {
      int i = q / 5, j = q % 5;
      idx |= x[t * 20 + q] << (19 - 4 * j - i);
    }
    if ((idx >> 12) == o) out[t] = s[PAD(idx & 4095)];
  }
#pragma unroll
  for (int i = 0; i < 4; ++i) {
    int f = (i * 256 + t) * 4;
    *(float4*)(psi + base + f) = *(const float4*)(s + PAD(f));
  }
}

// ---------------------------------------------------------------------------
extern "C" void kernel_launch(void* const* d_in, const int* in_sizes, int n_in,
                              void* d_out, int out_size, void* d_ws, size_t ws_size,
                              hipStream_t stream) {
  const int* x = (const int*)d_in[0];
  const float* peps = (const float*)d_in[1];
  const float* gate = (const float*)d_in[2];
  float* ws = (float*)d_ws;
  float* psi = ws + PSIO;
  float* out = (float*)d_out;

  k_build_cols<<<386, 256, 0, stream>>>(peps, ws);
  k_small<<<320, 256, 0, stream>>>(ws, ws + M01TO, ws + M34TO);
  k_t012<<<256, 256, 0, stream>>>(ws + M01TO, ws + COL2, ws + T12TO);
  k_psi0<<<256, 256, 0, stream>>>(ws + T12TO, ws + M34TO, psi);
  for (int it = 0; it < 5; ++it) {
    k_ha<<<256, 256, 0, stream>>>(psi, gate);        // H rows 2,3
    k_r01c01<<<64, 256, 0, stream>>>(psi, gate);     // H rows 0,1 + V cols 0,1
    if (it < 4)
      k_vall<false><<<256, 256, 0, stream>>>(psi, gate, x, out);
    else
      k_vall<true><<<256, 256, 0, stream>>>(psi, gate, x, out);
  }
}

// Round 8
// 309.739 us; speedup vs baseline: 1.0832x; 1.0832x over previous
//
#include <hip/hip_runtime.h>

// ---------------------------------------------------------------------------
// PEPS 4x5, D=4, P=2, depth-5 gate sweeps, 64-point gather.
// psi in COLUMN-major qubit order: qubit (i,j) at bit (19 - 4*j - i).
// 3 phases/iteration, all 16KB slab / grid 256:
//   A_k: [c1_{k-1}] + r2_k + r3_k   slab {17,16,15,14,13,12,9,8,5,4,1,0}
//   B_k: r0_k + r1_k + c0_k         slab {19,18,17,16,15,14,11,10,7,6,3,2}
//   C_k: c2,c3,c4                   slab {11..0}
//   D  : c1_4 + gather (no writeback)
// ---------------------------------------------------------------------------

#define PAD(i) ((i) + (((i) >> 4) << 2))   // +4 floats per 16 -> LDS bank spread
#define PIDX(i,j,p,u,d,l,r) (((((((i)*5+(j))*2+(p))*4+(u))*4+(d))*4+(l))*4+(r))

// workspace float offsets
static constexpr int COL0  = 0;                    // [16][256]
static constexpr int COL1  = 4096;                 // [16][256][256]
static constexpr int COL2  = COL1 + 1048576;
static constexpr int COL3  = COL2 + 1048576;
static constexpr int COL4  = COL3 + 1048576;       // [16][256]
static constexpr int M01TO = COL4 + 4096;          // [c01=256][R2=256]
static constexpr int M34TO = M01TO + 65536;        // [L3=256][c34=256]
static constexpr int T12TO = M34TO + 65536;        // [c2=16][c01=256][R3=256]
static constexpr int PSIO  = T12TO + 1048576;      // [2^20]

// --------------------------- column tensors --------------------------------
__global__ __launch_bounds__(256) void k_build_cols(const float* __restrict__ peps,
                                                    float* __restrict__ ws) {
  __shared__ float p01[4096], p23[4096];
  int bid = blockIdx.x, t = threadIdx.x;
  if (bid < 384) {
    int col = 1 + (bid >> 7);
    int part = bid & 127;
#pragma unroll
    for (int k = 0; k < 16; ++k) {
      int e = k * 256 + t;
      int r12 = e & 15, l12 = (e >> 4) & 15, d2 = (e >> 8) & 3, p = e >> 10;
      int l1 = l12 >> 2, l2 = l12 & 3, r1 = r12 >> 2, r2 = r12 & 3;
      float s01 = 0.f, s23 = 0.f;
#pragma unroll
      for (int d = 0; d < 4; ++d) {
        s01 += peps[PIDX(0, col, (p >> 1), 0, d, l1, r1)] *
               peps[PIDX(1, col, (p & 1), d, d2, l2, r2)];
        s23 += peps[PIDX(2, col, (p >> 1), d2, d, l1, r1)] *
               peps[PIDX(3, col, (p & 1), d, 0, l2, r2)];
      }
      p01[e] = s01;
      p23[e] = s23;
    }
    __syncthreads();
    const int coloffs[3] = {COL1, COL2, COL3};
    float* out = ws + coloffs[col - 1];
#pragma unroll
    for (int k = 0; k < 8; ++k) {
      int eq = part * 8192 + (k * 256 + t) * 4;
      int r34b = eq & 15;
      int r12 = (eq >> 4) & 15, l34 = (eq >> 8) & 15, l12 = (eq >> 12) & 15;
      int p = eq >> 16;
      int pa = p >> 2, pb = p & 3;
      float4 acc = {0.f, 0.f, 0.f, 0.f};
#pragma unroll
      for (int d2 = 0; d2 < 4; ++d2) {
        float a01 = p01[((((pa * 4 + d2) << 4) | l12) << 4) | r12];
        const float4 b4 =
            *(const float4*)&p23[((((pb * 4 + d2) << 4) | l34) << 4) | r34b];
        acc.x += a01 * b4.x;
        acc.y += a01 * b4.y;
        acc.z += a01 * b4.z;
        acc.w += a01 * b4.w;
      }
      *(float4*)&out[eq] = acc;
    }
  } else {
    int col = (bid == 384) ? 0 : 4;
    const int lsh = (col == 0) ? 0 : 2;
    const int rsh = (col == 4) ? 0 : 2;
    const int ldim = 1 << lsh, rdim = 1 << rsh;
    const int LLB = 2 * lsh, RRB = 2 * rsh;
    const int LL = 1 << LLB, RR = 1 << RRB;
    int n12 = (LL * RR) << 4;
    for (int e = t; e < n12; e += 256) {
      int r12 = e & (RR - 1);
      int l12 = (e >> RRB) & (LL - 1);
      int d2 = (e >> (RRB + LLB)) & 3;
      int p = e >> (RRB + LLB + 2);
      int l1 = l12 >> lsh, l2 = l12 & (ldim - 1);
      int r1 = r12 >> rsh, r2 = r12 & (rdim - 1);
      float s01 = 0.f, s23 = 0.f;
      for (int d = 0; d < 4; ++d) {
        s01 += peps[PIDX(0, col, (p >> 1), 0, d, l1, r1)] *
               peps[PIDX(1, col, (p & 1), d, d2, l2, r2)];
        s23 += peps[PIDX(2, col, (p >> 1), d2, d, l1, r1)] *
               peps[PIDX(3, col, (p & 1), d, 0, l2, r2)];
      }
      p01[e] = s01;
      p23[e] = s23;
    }
    __syncthreads();
    const int LB = 2 * LLB, RB = 2 * RRB;
    int total = 16 << (LB + RB);  // 4096
    float* out = ws + ((col == 0) ? COL0 : COL4);
    for (int e = t; e < total; e += 256) {
      int r = e & ((1 << RB) - 1);
      int l = (e >> RB) & ((1 << LB) - 1);
      int p = e >> (RB + LB);
      int r34 = r & (RR - 1), r12 = r >> RRB;
      int l34 = l & (LL - 1), l12 = l >> LLB;
      int pa = p >> 2, pb = p & 3;
      float s = 0.f;
      for (int d2 = 0; d2 < 4; ++d2) {
        s += p01[((((pa * 4 + d2) << LLB) | l12) << RRB) | r12] *
             p23[((((pb * 4 + d2) << LLB) | l34) << RRB) | r34];
      }
      out[e] = s;
    }
  }
}

// ------------------- M01 / M34T (edge-pair contractions) -------------------
__global__ __launch_bounds__(256) void k_small(const float* __restrict__ ws,
                                               float* __restrict__ m01,
                                               float* __restrict__ m34t) {
  __shared__ float c3buf[4112], c4buf[4112];
  int t = threadIdx.x;
  if (blockIdx.x < 64) {
    int c1 = blockIdx.x >> 2, q = blockIdx.x & 3;
    int r2l = t & 63, c0g = t >> 6;  // wave-uniform c0 group (4 c0 each)
    int R2 = q * 64 + r2l;
    const float* col0 = ws + COL0;
    const float* col1 = ws + COL1;
    float a0 = 0.f, a1 = 0.f, a2 = 0.f, a3 = 0.f;
    for (int R1 = 0; R1 < 256; ++R1) {
      float bv = col1[(c1 * 256 + R1) * 256 + R2];  // coalesced
      a0 += col0[(c0g * 4 + 0) * 256 + R1] * bv;    // uniform -> s_load
      a1 += col0[(c0g * 4 + 1) * 256 + R1] * bv;
      a2 += col0[(c0g * 4 + 2) * 256 + R1] * bv;
      a3 += col0[(c0g * 4 + 3) * 256 + R1] * bv;
    }
    m01[((c0g * 4 + 0) * 16 + c1) * 256 + R2] = a0;  // coalesced
    m01[((c0g * 4 + 1) * 16 + c1) * 256 + R2] = a1;
    m01[((c0g * 4 + 2) * 16 + c1) * 256 + R2] = a2;
    m01[((c0g * 4 + 3) * 16 + c1) * 256 + R2] = a3;
  } else {
    int L3 = blockIdx.x - 64;  // 0..255
    const float* col3 = ws + COL3;
    const float* col4 = ws + COL4;
    for (int e = t; e < 4096; e += 256) {
      c4buf[(e >> 8) * 257 + (e & 255)] = col4[e];
      c3buf[(e >> 8) * 257 + (e & 255)] =
          col3[(e >> 8) * 65536 + L3 * 256 + (e & 255)];
    }
    __syncthreads();
    int c3 = t >> 4, c4 = t & 15;
    float acc = 0.f;
    for (int B = 0; B < 256; ++B)
      acc += c3buf[c3 * 257 + B] * c4buf[c4 * 257 + B];
    m34t[L3 * 256 + t] = acc;
  }
}

// ---------------- T012[c2][c01][R3] = M01 x Col2 ---------------------------
__global__ __launch_bounds__(256) void k_t012(const float* __restrict__ m01,
                                              const float* __restrict__ col2,
                                              float* __restrict__ t012) {
  __shared__ float A[4096];  // [i=16][R2=256]
  int t = threadIdx.x;       // R3
  int c2 = blockIdx.x & 15, tg = blockIdx.x >> 4;
#pragma unroll
  for (int k = 0; k < 4; ++k)
    *(float4*)&A[(k * 256 + t) * 4] =
        *(const float4*)&m01[tg * 4096 + (k * 256 + t) * 4];
  __syncthreads();
  float acc[16] = {};
  for (int R2 = 0; R2 < 256; R2 += 4) {
    float b0 = col2[c2 * 65536 + (R2 + 0) * 256 + t];
    float b1 = col2[c2 * 65536 + (R2 + 1) * 256 + t];
    float b2 = col2[c2 * 65536 + (R2 + 2) * 256 + t];
    float b3 = col2[c2 * 65536 + (R2 + 3) * 256 + t];
#pragma unroll
    for (int i = 0; i < 16; ++i) {
      float4 a4 = *(const float4*)&A[i * 256 + R2];  // broadcast b128
      acc[i] += a4.x * b0 + a4.y * b1 + a4.z * b2 + a4.w * b3;
    }
  }
#pragma unroll
  for (int i = 0; i < 16; ++i)
    t012[c2 * 65536 + (tg * 16 + i) * 256 + t] = acc[i];  // coalesced
}

// ---------------- psi = T012 x M34T  (psi[(c01*16+c2)*256 + c34]) ----------
__global__ __launch_bounds__(256) void k_psi0(const float* __restrict__ t012,
                                              const float* __restrict__ m34t,
                                              float* __restrict__ psi) {
  __shared__ float A[4096];  // [i=c2=16][L3=256]
  int t = threadIdx.x;       // c34 (and L3 for staging)
  int tg = blockIdx.x;       // c01
#pragma unroll
  for (int i = 0; i < 16; ++i)
    A[i * 256 + t] = t012[i * 65536 + tg * 256 + t];  // coalesced 1KB chunks
  __syncthreads();
  float acc[16] = {};
  for (int L3 = 0; L3 < 256; L3 += 4) {
    float b0 = m34t[(L3 + 0) * 256 + t];
    float b1 = m34t[(L3 + 1) * 256 + t];
    float b2 = m34t[(L3 + 2) * 256 + t];
    float b3 = m34t[(L3 + 3) * 256 + t];
#pragma unroll
    for (int i = 0; i < 16; ++i) {
      float4 a4 = *(const float4*)&A[i * 256 + L3];  // broadcast b128
      acc[i] += a4.x * b0 + a4.y * b1 + a4.z * b2 + a4.w * b3;
    }
  }
#pragma unroll
  for (int i = 0; i < 16; ++i)
    psi[(tg * 16 + i) * 256 + t] = acc[i];  // coalesced
}

// ---------------- register-level 2-qubit gate ------------------------------
template <int NB, int HI, int LO>
__device__ __forceinline__ void gate2(float* x, const float* __restrict__ g) {
  constexpr int H = 1 << HI, L = 1 << LO, N = 1 << NB;
#pragma unroll
  for (int o = 0; o < N; ++o) {
    if (o & (H | L)) continue;
    float v0 = x[o], v1 = x[o + L], v2 = x[o + H], v3 = x[o + H + L];
    x[o]         = g[0]  * v0 + g[1]  * v1 + g[2]  * v2 + g[3]  * v3;
    x[o + L]     = g[4]  * v0 + g[5]  * v1 + g[6]  * v2 + g[7]  * v3;
    x[o + H]     = g[8]  * v0 + g[9]  * v1 + g[10] * v2 + g[11] * v3;
    x[o + H + L] = g[12] * v0 + g[13] * v1 + g[14] * v2 + g[15] * v3;
  }
}

// H row transform: 5-bit group, S4 = leftmost column (j=0); bonds (4,3)..(1,0)
template <int S4, int S3, int S2, int S1, int S0>
__device__ __forceinline__ void hxf(float* s, const float* __restrict__ g, int b) {
  float x[32];
#pragma unroll
  for (int m = 0; m < 32; ++m) {
    int off = ((m >> 4) & 1) * S4 + ((m >> 3) & 1) * S3 + ((m >> 2) & 1) * S2 +
              ((m >> 1) & 1) * S1 + (m & 1) * S0;
    x[m] = s[PAD(b + off)];
  }
  gate2<5, 4, 3>(x, g);
  gate2<5, 3, 2>(x, g);
  gate2<5, 2, 1>(x, g);
  gate2<5, 1, 0>(x, g);
#pragma unroll
  for (int m = 0; m < 32; ++m) {
    int off = ((m >> 4) & 1) * S4 + ((m >> 3) & 1) * S3 + ((m >> 2) & 1) * S2 +
              ((m >> 1) & 1) * S1 + (m & 1) * S0;
    s[PAD(b + off)] = x[m];
  }
}

// V column transform: 4-bit nibble, bit3 = row 0; bonds (3,2),(2,1),(1,0)
template <int ST>
__device__ __forceinline__ void vxf(float* s, const float* __restrict__ g, int b) {
  float x[16];
#pragma unroll
  for (int m = 0; m < 16; ++m) x[m] = s[PAD(b + m * ST)];
  gate2<4, 3, 2>(x, g);
  gate2<4, 2, 1>(x, g);
  gate2<4, 1, 0>(x, g);
#pragma unroll
  for (int m = 0; m < 16; ++m) s[PAD(b + m * ST)] = x[m];
}

// Phase A: [c1 prev] + r2 + r3.
// slab n11..0 = psi bits {17,16,15,14,13,12,9,8,5,4,1,0}
// outer o7..0 = psi bits {19,18,11,10,7,6,3,2}
template <bool DO_C1>
__global__ __launch_bounds__(256) void k_A(float* __restrict__ psi,
                                           const float* __restrict__ gate) {
  __shared__ float s[5120];
  float g[16];
#pragma unroll
  for (int i = 0; i < 16; ++i) g[i] = gate[i];
  int t = threadIdx.x;
  int o = blockIdx.x;
  int base = ((o >> 6) & 3) * 262144 + ((o >> 4) & 3) * 1024 +
             ((o >> 2) & 3) * 64 + (o & 3) * 4;
#pragma unroll
  for (int i = 0; i < 4; ++i) {
    int f = (i * 256 + t) * 4;  // f&3 == 0 -> psi bits 1,0 -> float4 contiguous
    int addr = (f >> 8) * 16384 + ((f >> 6) & 3) * 4096 + ((f >> 4) & 3) * 256 +
               ((f >> 2) & 3) * 16 + base;
    *(float4*)(s + PAD(f)) = *(const float4*)(psi + addr);
  }
  __syncthreads();
  if (DO_C1) {
    // c1: psi {15,14,13,12} = n{9,8,7,6}, stride 64; free n{11,10,5..0}
    vxf<64>(s, g, ((t >> 6) & 3) * 1024 + (t & 63));
    __syncthreads();
  }
  if (t < 128) {  // r2: psi {17,13,9,5,1} = n{11,7,5,3,1}; free n{10,9,8,6,4,2,0}
    int b = ((t >> 6) & 1) * 1024 + ((t >> 5) & 1) * 512 + ((t >> 4) & 1) * 256 +
            ((t >> 3) & 1) * 64 + ((t >> 2) & 1) * 16 + ((t >> 1) & 1) * 4 + (t & 1);
    hxf<2048, 128, 32, 8, 2>(s, g, b);
  }
  __syncthreads();
  if (t < 128) {  // r3: psi {16,12,8,4,0} = n{10,6,4,2,0}; free n{11,9,8,7,5,3,1}
    int b = ((t >> 6) & 1) * 2048 + ((t >> 5) & 1) * 512 + ((t >> 4) & 1) * 256 +
            ((t >> 3) & 1) * 128 + ((t >> 2) & 1) * 32 + ((t >> 1) & 1) * 8 +
            (t & 1) * 2;
    hxf<1024, 64, 16, 4, 1>(s, g, b);
  }
  __syncthreads();
#pragma unroll
  for (int i = 0; i < 4; ++i) {
    int f = (i * 256 + t) * 4;
    int addr = (f >> 8) * 16384 + ((f >> 6) & 3) * 4096 + ((f >> 4) & 3) * 256 +
               ((f >> 2) & 3) * 16 + base;
    *(float4*)(psi + addr) = *(const float4*)(s + PAD(f));
  }
}

// Phase B: r0 + r1 + c0.
// slab n11..0 = psi bits {19,18,17,16,15,14,11,10,7,6,3,2}
// outer o7..0 = psi bits {13,12,9,8,5,4,1,0}
__global__ __launch_bounds__(256) void k_B(float* __restrict__ psi,
                                           const float* __restrict__ gate) {
  __shared__ float s[5120];
  float g[16];
#pragma unroll
  for (int i = 0; i < 16; ++i) g[i] = gate[i];
  int t = threadIdx.x;
  int o = blockIdx.x;
  int base = (o & 3) + ((o >> 2) & 3) * 16 + ((o >> 4) & 3) * 256 +
             (o >> 6) * 4096;
#pragma unroll
  for (int k = 0; k < 16; ++k) {  // scalar loads, stride 4 (bits 1,0 are outer)
    int n = k * 256 + t;
    int addr = (n & 3) * 4 + ((n >> 2) & 3) * 64 + ((n >> 4) & 3) * 1024 +
               ((n >> 6) & 3) * 16384 + (n >> 8) * 65536 + base;
    s[PAD(n)] = psi[addr];
  }
  __syncthreads();
  if (t < 128) {  // r0: psi {19,15,11,7,3} = n{11,7,5,3,1}; free n{10,9,8,6,4,2,0}
    int b = ((t >> 6) & 1) * 1024 + ((t >> 5) & 1) * 512 + ((t >> 4) & 1) * 256 +
            ((t >> 3) & 1) * 64 + ((t >> 2) & 1) * 16 + ((t >> 1) & 1) * 4 + (t & 1);
    hxf<2048, 128, 32, 8, 2>(s, g, b);
  }
  __syncthreads();
  if (t < 128) {  // r1: psi {18,14,10,6,2} = n{10,6,4,2,0}; free n{11,9,8,7,5,3,1}
    int b = ((t >> 6) & 1) * 2048 + ((t >> 5) & 1) * 512 + ((t >> 4) & 1) * 256 +
            ((t >> 3) & 1) * 128 + ((t >> 2) & 1) * 32 + ((t >> 1) & 1) * 8 +
            (t & 1) * 2;
    hxf<1024, 64, 16, 4, 1>(s, g, b);
  }
  __syncthreads();
  // c0: psi {19,18,17,16} = n{11,10,9,8}, stride 256; free n7..0 = t
  vxf<256>(s, g, t);
  __syncthreads();
#pragma unroll
  for (int k = 0; k < 16; ++k) {
    int n = k * 256 + t;
    int addr = (n & 3) * 4 + ((n >> 2) & 3) * 64 + ((n >> 4) & 3) * 1024 +
               ((n >> 6) & 3) * 16384 + (n >> 8) * 65536 + base;
    psi[addr] = s[PAD(n)];
  }
}

// Phase C: c2,c3,c4 ; slab = psi bits 11..0, outer = bits 19..12.
__global__ __launch_bounds__(256) void k_C(float* __restrict__ psi,
                                           const float* __restrict__ gate) {
  __shared__ float s[5120];
  float g[16];
#pragma unroll
  for (int i = 0; i < 16; ++i) g[i] = gate[i];
  int t = threadIdx.x;
  int base = blockIdx.x * 4096;
#pragma unroll
  for (int i = 0; i < 4; ++i) {
    int f = (i * 256 + t) * 4;
    *(float4*)(s + PAD(f)) = *(const float4*)(psi + base + f);
  }
  __syncthreads();
  vxf<256>(s, g, t);                             // c2 (bits 11..8)
  __syncthreads();
  vxf<16>(s, g, ((t >> 4) << 8) | (t & 15));     // c3 (bits 7..4)
  __syncthreads();
  vxf<1>(s, g, t * 16);                          // c4 (bits 3..0)
  __syncthreads();
#pragma unroll
  for (int i = 0; i < 4; ++i) {
    int f = (i * 256 + t) * 4;
    *(float4*)(psi + base + f) = *(const float4*)(s + PAD(f));
  }
}

// Phase D (final): c1 of last iteration + gather. No psi writeback needed.
// slab n11..8 = psi bits 15..12, n7..0 = psi bits 7..0
// outer o7..4 = psi bits 19..16, o3..0 = psi bits 11..8
__global__ __launch_bounds__(256) void k_D(const float* __restrict__ psi,
                                           const float* __restrict__ gate,
                                           const int* __restrict__ x,
                                           float* __restrict__ out) {
  __shared__ float s[5120];
  float g[16];
#pragma unroll
  for (int i = 0; i < 16; ++i) g[i] = gate[i];
  int t = threadIdx.x;
  int o = blockIdx.x;
  int base = (o >> 4) * 65536 + (o & 15) * 256;
#pragma unroll
  for (int i = 0; i < 4; ++i) {
    int f = (i * 256 + t) * 4;
    int addr = (f >> 8) * 4096 + (f & 255) + base;
    *(float4*)(s + PAD(f)) = *(const float4*)(psi + addr);
  }
  __syncthreads();
  // c1: psi {15,14,13,12} = n{11,10,9,8}, stride 256; free n7..0 = t
  vxf<256>(s, g, t);
  __syncthreads();
  if (t < 64) {
    int idx = 0;
#pragma unroll
    for (int q = 0; q < 20; ++q) {
      int i = q / 5, j = q % 5;
      idx |= x[t * 20 + q] << (19 - 4 * j - i);
    }
    int o_idx = (((idx >> 16) & 15) << 4) | ((idx >> 8) & 15);
    if (o_idx == o)
      out[t] = s[PAD((((idx >> 12) & 15) << 8) | (idx & 255))];
  }
}

// ---------------------------------------------------------------------------
extern "C" void kernel_launch(void* const* d_in, const int* in_sizes, int n_in,
                              void* d_out, int out_size, void* d_ws, size_t ws_size,
                              hipStream_t stream) {
  const int* x = (const int*)d_in[0];
  const float* peps = (const float*)d_in[1];
  const float* gate = (const float*)d_in[2];
  float* ws = (float*)d_ws;
  float* psi = ws + PSIO;
  float* out = (float*)d_out;

  k_build_cols<<<386, 256, 0, stream>>>(peps, ws);
  k_small<<<320, 256, 0, stream>>>(ws, ws + M01TO, ws + M34TO);
  k_t012<<<256, 256, 0, stream>>>(ws + M01TO, ws + COL2, ws + T12TO);
  k_psi0<<<256, 256, 0, stream>>>(ws + T12TO, ws + M34TO, psi);

  k_A<false><<<256, 256, 0, stream>>>(psi, gate);  // r2,r3 (iter 0)
  k_B<<<256, 256, 0, stream>>>(psi, gate);         // r0,r1,c0
  k_C<<<256, 256, 0, stream>>>(psi, gate);         // c2,c3,c4
  for (int it = 1; it < 5; ++it) {
    k_A<true><<<256, 256, 0, stream>>>(psi, gate); // c1(prev), r2,r3
    k_B<<<256, 256, 0, stream>>>(psi, gate);
    k_C<<<256, 256, 0, stream>>>(psi, gate);
  }
  k_D<<<256, 256, 0, stream>>>(psi, gate, x, out); // c1(last) + gather
}

// Round 9
// 221.622 us; speedup vs baseline: 1.5139x; 1.3976x over previous
//
#include <hip/hip_runtime.h>

// ---------------------------------------------------------------------------
// PEPS 4x5, D=4, P=2, depth-5 gate sweeps, 64-point gather.
// Gate layout: psi_new idx = n3*2^16 + n4*2^12 + n0*2^8 + n1*2^4 + n2,
// nibble n_j = column j, nibble bit (3-i) = row i.
// Per iteration (H sweep = G2_01 G2_12 G2_23 G2_34; V sweep = M16_j):
//   P1: G2_01, G2_12, M16_0, M16_1   (slab = low 12 bits, contiguous)
//   P2: G2_23, G2_34, M16_2..4       (slab = bits {19..12,3..0}, 64B runs)
// M16_0/1 commute with G2_23/34 (disjoint columns) -> exact reorder.
// ---------------------------------------------------------------------------

#define PAD(i) ((i) + (((i) >> 4) << 2))   // +4 floats per 16 -> LDS bank spread
#define PIDX(i,j,p,u,d,l,r) (((((((i)*5+(j))*2+(p))*4+(u))*4+(d))*4+(l))*4+(r))

// workspace float offsets
static constexpr int COL0  = 0;                    // [16][256]
static constexpr int COL1  = 4096;                 // [16][256][256]
static constexpr int COL2  = COL1 + 1048576;
static constexpr int COL3  = COL2 + 1048576;
static constexpr int COL4  = COL3 + 1048576;       // [16][256]
static constexpr int M01TO = COL4 + 4096;          // [c01=256][R2=256]
static constexpr int M34TO = M01TO + 65536;        // [L3=256][c34=256]
static constexpr int T12TO = M34TO + 65536;        // [c2=16][c01=256][R3=256]
static constexpr int PSIO  = T12TO + 1048576;      // [2^20] (old layout)
// psi_new reuses T12TO after k_psi0 consumes t012.

// --------------------------- column tensors --------------------------------
__global__ __launch_bounds__(256) void k_build_cols(const float* __restrict__ peps,
                                                    float* __restrict__ ws) {
  __shared__ float p01[4096], p23[4096];
  int bid = blockIdx.x, t = threadIdx.x;
  if (bid < 384) {
    int col = 1 + (bid >> 7);
    int part = bid & 127;
#pragma unroll
    for (int k = 0; k < 16; ++k) {
      int e = k * 256 + t;
      int r12 = e & 15, l12 = (e >> 4) & 15, d2 = (e >> 8) & 3, p = e >> 10;
      int l1 = l12 >> 2, l2 = l12 & 3, r1 = r12 >> 2, r2 = r12 & 3;
      float s01 = 0.f, s23 = 0.f;
#pragma unroll
      for (int d = 0; d < 4; ++d) {
        s01 += peps[PIDX(0, col, (p >> 1), 0, d, l1, r1)] *
               peps[PIDX(1, col, (p & 1), d, d2, l2, r2)];
        s23 += peps[PIDX(2, col, (p >> 1), d2, d, l1, r1)] *
               peps[PIDX(3, col, (p & 1), d, 0, l2, r2)];
      }
      p01[e] = s01;
      p23[e] = s23;
    }
    __syncthreads();
    const int coloffs[3] = {COL1, COL2, COL3};
    float* out = ws + coloffs[col - 1];
#pragma unroll
    for (int k = 0; k < 8; ++k) {
      int eq = part * 8192 + (k * 256 + t) * 4;
      int r34b = eq & 15;
      int r12 = (eq >> 4) & 15, l34 = (eq >> 8) & 15, l12 = (eq >> 12) & 15;
      int p = eq >> 16;
      int pa = p >> 2, pb = p & 3;
      float4 acc = {0.f, 0.f, 0.f, 0.f};
#pragma unroll
      for (int d2 = 0; d2 < 4; ++d2) {
        float a01 = p01[((((pa * 4 + d2) << 4) | l12) << 4) | r12];
        const float4 b4 =
            *(const float4*)&p23[((((pb * 4 + d2) << 4) | l34) << 4) | r34b];
        acc.x += a01 * b4.x;
        acc.y += a01 * b4.y;
        acc.z += a01 * b4.z;
        acc.w += a01 * b4.w;
      }
      *(float4*)&out[eq] = acc;
    }
  } else {
    int col = (bid == 384) ? 0 : 4;
    const int lsh = (col == 0) ? 0 : 2;
    const int rsh = (col == 4) ? 0 : 2;
    const int ldim = 1 << lsh, rdim = 1 << rsh;
    const int LLB = 2 * lsh, RRB = 2 * rsh;
    const int LL = 1 << LLB, RR = 1 << RRB;
    int n12 = (LL * RR) << 4;
    for (int e = t; e < n12; e += 256) {
      int r12 = e & (RR - 1);
      int l12 = (e >> RRB) & (LL - 1);
      int d2 = (e >> (RRB + LLB)) & 3;
      int p = e >> (RRB + LLB + 2);
      int l1 = l12 >> lsh, l2 = l12 & (ldim - 1);
      int r1 = r12 >> rsh, r2 = r12 & (rdim - 1);
      float s01 = 0.f, s23 = 0.f;
      for (int d = 0; d < 4; ++d) {
        s01 += peps[PIDX(0, col, (p >> 1), 0, d, l1, r1)] *
               peps[PIDX(1, col, (p & 1), d, d2, l2, r2)];
        s23 += peps[PIDX(2, col, (p >> 1), d2, d, l1, r1)] *
               peps[PIDX(3, col, (p & 1), d, 0, l2, r2)];
      }
      p01[e] = s01;
      p23[e] = s23;
    }
    __syncthreads();
    const int LB = 2 * LLB, RB = 2 * RRB;
    int total = 16 << (LB + RB);  // 4096
    float* out = ws + ((col == 0) ? COL0 : COL4);
    for (int e = t; e < total; e += 256) {
      int r = e & ((1 << RB) - 1);
      int l = (e >> RB) & ((1 << LB) - 1);
      int p = e >> (RB + LB);
      int r34 = r & (RR - 1), r12 = r >> RRB;
      int l34 = l & (LL - 1), l12 = l >> LLB;
      int pa = p >> 2, pb = p & 3;
      float s = 0.f;
      for (int d2 = 0; d2 < 4; ++d2) {
        s += p01[((((pa * 4 + d2) << LLB) | l12) << RRB) | r12] *
             p23[((((pb * 4 + d2) << LLB) | l34) << RRB) | r34];
      }
      out[e] = s;
    }
  }
}

// ------------------- M01 / M34T (edge-pair contractions) -------------------
__global__ __launch_bounds__(256) void k_small(const float* __restrict__ ws,
                                               float* __restrict__ m01,
                                               float* __restrict__ m34t) {
  __shared__ float c3buf[4112], c4buf[4112];
  int t = threadIdx.x;
  if (blockIdx.x < 64) {
    int c1 = blockIdx.x >> 2, q = blockIdx.x & 3;
    int r2l = t & 63, c0g = t >> 6;  // wave-uniform c0 group (4 c0 each)
    int R2 = q * 64 + r2l;
    const float* col0 = ws + COL0;
    const float* col1 = ws + COL1;
    float a0 = 0.f, a1 = 0.f, a2 = 0.f, a3 = 0.f;
    for (int R1 = 0; R1 < 256; ++R1) {
      float bv = col1[(c1 * 256 + R1) * 256 + R2];  // coalesced
      a0 += col0[(c0g * 4 + 0) * 256 + R1] * bv;    // uniform -> s_load
      a1 += col0[(c0g * 4 + 1) * 256 + R1] * bv;
      a2 += col0[(c0g * 4 + 2) * 256 + R1] * bv;
      a3 += col0[(c0g * 4 + 3) * 256 + R1] * bv;
    }
    m01[((c0g * 4 + 0) * 16 + c1) * 256 + R2] = a0;  // coalesced
    m01[((c0g * 4 + 1) * 16 + c1) * 256 + R2] = a1;
    m01[((c0g * 4 + 2) * 16 + c1) * 256 + R2] = a2;
    m01[((c0g * 4 + 3) * 16 + c1) * 256 + R2] = a3;
  } else {
    int L3 = blockIdx.x - 64;  // 0..255
    const float* col3 = ws + COL3;
    const float* col4 = ws + COL4;
    for (int e = t; e < 4096; e += 256) {
      c4buf[(e >> 8) * 257 + (e & 255)] = col4[e];
      c3buf[(e >> 8) * 257 + (e & 255)] =
          col3[(e >> 8) * 65536 + L3 * 256 + (e & 255)];
    }
    __syncthreads();
    int c3 = t >> 4, c4 = t & 15;
    float acc = 0.f;
    for (int B = 0; B < 256; ++B)
      acc += c3buf[c3 * 257 + B] * c4buf[c4 * 257 + B];
    m34t[L3 * 256 + t] = acc;
  }
}

// ---------------- T012[c2][c01][R3] = M01 x Col2 ---------------------------
__global__ __launch_bounds__(256) void k_t012(const float* __restrict__ m01,
                                              const float* __restrict__ col2,
                                              float* __restrict__ t012) {
  __shared__ float A[4096];  // [i=16][R2=256]
  int t = threadIdx.x;       // R3
  int c2 = blockIdx.x & 15, tg = blockIdx.x >> 4;
#pragma unroll
  for (int k = 0; k < 4; ++k)
    *(float4*)&A[(k * 256 + t) * 4] =
        *(const float4*)&m01[tg * 4096 + (k * 256 + t) * 4];
  __syncthreads();
  float acc[16] = {};
  for (int R2 = 0; R2 < 256; R2 += 4) {
    float b0 = col2[c2 * 65536 + (R2 + 0) * 256 + t];
    float b1 = col2[c2 * 65536 + (R2 + 1) * 256 + t];
    float b2 = col2[c2 * 65536 + (R2 + 2) * 256 + t];
    float b3 = col2[c2 * 65536 + (R2 + 3) * 256 + t];
#pragma unroll
    for (int i = 0; i < 16; ++i) {
      float4 a4 = *(const float4*)&A[i * 256 + R2];  // broadcast b128
      acc[i] += a4.x * b0 + a4.y * b1 + a4.z * b2 + a4.w * b3;
    }
  }
#pragma unroll
  for (int i = 0; i < 16; ++i)
    t012[c2 * 65536 + (tg * 16 + i) * 256 + t] = acc[i];  // coalesced
}

// ---------------- psi_old = T012 x M34T  (old layout, coalesced) -----------
__global__ __launch_bounds__(256) void k_psi0(const float* __restrict__ t012,
                                              const float* __restrict__ m34t,
                                              float* __restrict__ psi) {
  __shared__ float A[4096];  // [i=c2=16][L3=256]
  int t = threadIdx.x;       // c34 (and L3 for staging)
  int tg = blockIdx.x;       // c01
#pragma unroll
  for (int i = 0; i < 16; ++i)
    A[i * 256 + t] = t012[i * 65536 + tg * 256 + t];  // coalesced 1KB chunks
  __syncthreads();
  float acc[16] = {};
  for (int L3 = 0; L3 < 256; L3 += 4) {
    float b0 = m34t[(L3 + 0) * 256 + t];
    float b1 = m34t[(L3 + 1) * 256 + t];
    float b2 = m34t[(L3 + 2) * 256 + t];
    float b3 = m34t[(L3 + 3) * 256 + t];
#pragma unroll
    for (int i = 0; i < 16; ++i) {
      float4 a4 = *(const float4*)&A[i * 256 + L3];  // broadcast b128
      acc[i] += a4.x * b0 + a4.y * b1 + a4.z * b2 + a4.w * b3;
    }
  }
#pragma unroll
  for (int i = 0; i < 16; ++i)
    psi[(tg * 16 + i) * 256 + t] = acc[i];  // coalesced
}

// ---------------- register-level 2-qubit gate ------------------------------
template <int NB, int HI, int LO>
__device__ __forceinline__ void gate2(float* x, const float* __restrict__ g) {
  constexpr int H = 1 << HI, L = 1 << LO, N = 1 << NB;
#pragma unroll
  for (int o = 0; o < N; ++o) {
    if (o & (H | L)) continue;
    float v0 = x[o], v1 = x[o + L], v2 = x[o + H], v3 = x[o + H + L];
    x[o]         = g[0]  * v0 + g[1]  * v1 + g[2]  * v2 + g[3]  * v3;
    x[o + L]     = g[4]  * v0 + g[5]  * v1 + g[6]  * v2 + g[7]  * v3;
    x[o + H]     = g[8]  * v0 + g[9]  * v1 + g[10] * v2 + g[11] * v3;
    x[o + H + L] = g[12] * v0 + g[13] * v1 + g[14] * v2 + g[15] * v3;
  }
}

// V column transform: 4-bit nibble, x bit3 = row 0; bonds (3,2),(2,1),(1,0)
template <int ST>
__device__ __forceinline__ void vxf(float* s, const float* __restrict__ g, int b) {
  float x[16];
#pragma unroll
  for (int m = 0; m < 16; ++m) x[m] = s[PAD(b + m * ST)];
  gate2<4, 3, 2>(x, g);
  gate2<4, 2, 1>(x, g);
  gate2<4, 1, 0>(x, g);
#pragma unroll
  for (int m = 0; m < 16; ++m) s[PAD(b + m * ST)] = x[m];
}

// Bond-pair round: apply gate on slab-bit pair (B2,B1), then (B1,B0).
// 8-elem register groups; 512 groups/slab -> 2 per thread.
template <int B2, int B1, int B0>
__device__ __forceinline__ void bondpair(float* s, const float* __restrict__ g,
                                         int t) {
  constexpr int MASK = (1 << B2) | (1 << B1) | (1 << B0);
#pragma unroll
  for (int k = 0; k < 2; ++k) {
    int gi = k * 256 + t;
    int b = 0, rem = gi;
#pragma unroll
    for (int p = 0; p < 12; ++p) {
      if (!((MASK >> p) & 1)) {
        b |= (rem & 1) << p;
        rem >>= 1;
      }
    }
    float x[8];
#pragma unroll
    for (int m = 0; m < 8; ++m) {
      int off = ((m >> 2) & 1) * (1 << B2) + ((m >> 1) & 1) * (1 << B1) +
                (m & 1) * (1 << B0);
      x[m] = s[PAD(b + off)];
    }
    gate2<3, 2, 1>(x, g);  // bond (B2, B1)
    gate2<3, 1, 0>(x, g);  // bond (B1, B0)
#pragma unroll
    for (int m = 0; m < 8; ++m) {
      int off = ((m >> 2) & 1) * (1 << B2) + ((m >> 1) & 1) * (1 << B1) +
                (m & 1) * (1 << B0);
      s[PAD(b + off)] = x[m];
    }
  }
}

// Phase P1: G2_01, G2_12, M16_0, M16_1.
// slab local: n0 = bits 11..8, n1 = 7..4, n2 = 3..0; outer o = (n3,n4).
// FIRST: read old layout [c0 c1 c2 c3 c4] scattered, write new layout.
template <bool FIRST>
__global__ __launch_bounds__(256) void k_P1(const float* __restrict__ src,
                                            float* __restrict__ dst,
                                            const float* __restrict__ gate) {
  __shared__ float s[5120];
  float g[16];
#pragma unroll
  for (int i = 0; i < 16; ++i) g[i] = gate[i];
  int t = threadIdx.x;
  int o;
  if (FIRST) {
    o = ((blockIdx.x & 7) << 5) | (blockIdx.x >> 3);  // XCD-local o runs
#pragma unroll
    for (int k = 0; k < 16; ++k) {
      int n = k * 256 + t;
      int addr = (n >> 8) * 65536 + ((n >> 4) & 15) * 4096 + (n & 15) * 256 +
                 (o >> 4) * 16 + (o & 15);
      s[PAD(n)] = src[addr];
    }
  } else {
    o = blockIdx.x;
#pragma unroll
    for (int i = 0; i < 4; ++i) {
      int f = (i * 256 + t) * 4;
      *(float4*)(s + PAD(f)) = *(const float4*)(src + o * 4096 + f);
    }
  }
  __syncthreads();
  // G2_01 + G2_12, row r: bits (8+q, 4+q, q), q = 3-r
  bondpair<8, 4, 0>(s, g, t);
  __syncthreads();
  bondpair<9, 5, 1>(s, g, t);
  __syncthreads();
  bondpair<10, 6, 2>(s, g, t);
  __syncthreads();
  bondpair<11, 7, 3>(s, g, t);
  __syncthreads();
  vxf<256>(s, g, t);                           // M16_0 (n0, bits 11..8)
  __syncthreads();
  vxf<16>(s, g, ((t >> 4) << 8) | (t & 15));   // M16_1 (n1, bits 7..4)
  __syncthreads();
#pragma unroll
  for (int i = 0; i < 4; ++i) {
    int f = (i * 256 + t) * 4;
    *(float4*)(dst + o * 4096 + f) = *(const float4*)(s + PAD(f));
  }
}

// Phase P2: G2_23, G2_34, M16_2, M16_3, M16_4.
// slab local: n3 = bits 11..8, n4 = 7..4, n2 = 3..0; outer o = (n0,n1).
// LAST: gather into out, skip psi writeback.
template <bool LAST>
__global__ __launch_bounds__(256) void k_P2(float* __restrict__ psi,
                                            const float* __restrict__ gate,
                                            const int* __restrict__ x,
                                            float* __restrict__ out) {
  __shared__ float s[5120];
  float g[16];
#pragma unroll
  for (int i = 0; i < 16; ++i) g[i] = gate[i];
  int t = threadIdx.x;
  int o = blockIdx.x;
#pragma unroll
  for (int i = 0; i < 4; ++i) {
    int f = (i * 256 + t) * 4;
    int addr = (f >> 8) * 65536 + ((f >> 4) & 15) * 4096 + o * 16 + (f & 15);
    *(float4*)(s + PAD(f)) = *(const float4*)(psi + addr);
  }
  __syncthreads();
  // G2_23 + G2_34, row r: bits (q, 8+q, 4+q), q = 3-r
  bondpair<0, 8, 4>(s, g, t);
  __syncthreads();
  bondpair<1, 9, 5>(s, g, t);
  __syncthreads();
  bondpair<2, 10, 6>(s, g, t);
  __syncthreads();
  bondpair<3, 11, 7>(s, g, t);
  __syncthreads();
  vxf<1>(s, g, t * 16);                        // M16_2 (n2, bits 3..0)
  __syncthreads();
  vxf<256>(s, g, t);                           // M16_3 (n3, bits 11..8)
  __syncthreads();
  vxf<16>(s, g, ((t >> 4) << 8) | (t & 15));   // M16_4 (n4, bits 7..4)
  __syncthreads();
  if (LAST) {
    if (t < 64) {
      int idx = 0;
#pragma unroll
      for (int q = 0; q < 20; ++q) {
        int i = q / 5, j = q % 5;
        int pos = (j == 0) ? (11 - i)
                 : (j == 1) ? (7 - i)
                 : (j == 2) ? (3 - i)
                 : (j == 3) ? (19 - i)
                            : (15 - i);
        idx |= x[t * 20 + q] << pos;
      }
      if (((idx >> 4) & 255) == o) {
        int local = ((idx >> 16) & 15) * 256 + ((idx >> 12) & 15) * 16 +
                    (idx & 15);
        out[t] = s[PAD(local)];
      }
    }
  } else {
#pragma unroll
    for (int i = 0; i < 4; ++i) {
      int f = (i * 256 + t) * 4;
      int addr = (f >> 8) * 65536 + ((f >> 4) & 15) * 4096 + o * 16 + (f & 15);
      *(float4*)(psi + addr) = *(const float4*)(s + PAD(f));
    }
  }
}

// ---------------------------------------------------------------------------
extern "C" void kernel_launch(void* const* d_in, const int* in_sizes, int n_in,
                              void* d_out, int out_size, void* d_ws, size_t ws_size,
                              hipStream_t stream) {
  const int* x = (const int*)d_in[0];
  const float* peps = (const float*)d_in[1];
  const float* gate = (const float*)d_in[2];
  float* ws = (float*)d_ws;
  float* psi_old = ws + PSIO;
  float* psi_new = ws + T12TO;  // t012 buffer is dead after k_psi0
  float* out = (float*)d_out;

  k_build_cols<<<386, 256, 0, stream>>>(peps, ws);
  k_small<<<320, 256, 0, stream>>>(ws, ws + M01TO, ws + M34TO);
  k_t012<<<256, 256, 0, stream>>>(ws + M01TO, ws + COL2, ws + T12TO);
  k_psi0<<<256, 256, 0, stream>>>(ws + T12TO, ws + M34TO, psi_old);
  // NOTE: psi_new aliases t012 — k_P1<true> reads psi_old only, safe.

  k_P1<true><<<256, 256, 0, stream>>>(psi_old, psi_new, gate);
  k_P2<false><<<256, 256, 0, stream>>>(psi_new, gate, x, out);
  for (int it = 1; it < 5; ++it) {
    k_P1<false><<<256, 256, 0, stream>>>(psi_new, psi_new, gate);
    if (it < 4)
      k_P2<false><<<256, 256, 0, stream>>>(psi_new, gate, x, out);
    else
      k_P2<true><<<256, 256, 0, stream>>>(psi_new, gate, x, out);
  }
}

// Round 10
// 214.622 us; speedup vs baseline: 1.5633x; 1.0326x over previous
//
#include <hip/hip_runtime.h>

// ---------------------------------------------------------------------------
// PEPS 4x5, D=4, P=2, depth-5 gate sweeps, 64-point gather.
// Gate layout: psi idx = c3<<16 | c4<<12 | c0<<8 | c1<<4 | c2,
// nibble c_j = column j, nibble bit (3-i) = row i.
// Per iteration (H sweep = G2_01 G2_12 G2_23 G2_34; V sweep = M16_j):
//   P1: G2_01, G2_12, M16_0, M16_1   (slab = low 12 bits, contiguous)
//   P2: G2_23, G2_34, M16_2..4       (slab = bits {19..12,3..0}, 64B runs)
// M16_0/1 commute with G2_23/34 (disjoint columns) -> exact reorder.
// k_psi0 emits the gate layout directly (LDS transpose, 64B-run stores).
// ---------------------------------------------------------------------------

#define PAD(i) ((i) + (((i) >> 4) << 2))   // +4 floats per 16 -> LDS bank spread
#define PIDX(i,j,p,u,d,l,r) (((((((i)*5+(j))*2+(p))*4+(u))*4+(d))*4+(l))*4+(r))

// workspace float offsets
static constexpr int COL0  = 0;                    // [16][256]
static constexpr int COL1  = 4096;                 // [16][256][256]
static constexpr int COL2  = COL1 + 1048576;
static constexpr int COL3  = COL2 + 1048576;
static constexpr int COL4  = COL3 + 1048576;       // [16][256]
static constexpr int M01TO = COL4 + 4096;          // [c01=256][R2=256]
static constexpr int M34TO = M01TO + 65536;        // [L3=256][c34=256]
static constexpr int T12TO = M34TO + 65536;        // [c2=16][c01=256][R3=256]
static constexpr int PSIO  = T12TO + 1048576;      // [2^20] gate layout

// --------------------------- column tensors --------------------------------
__global__ __launch_bounds__(256) void k_build_cols(const float* __restrict__ peps,
                                                    float* __restrict__ ws) {
  __shared__ float p01[4096], p23[4096];
  int bid = blockIdx.x, t = threadIdx.x;
  if (bid < 384) {
    int col = 1 + (bid >> 7);
    int part = bid & 127;
#pragma unroll
    for (int k = 0; k < 16; ++k) {
      int e = k * 256 + t;
      int r12 = e & 15, l12 = (e >> 4) & 15, d2 = (e >> 8) & 3, p = e >> 10;
      int l1 = l12 >> 2, l2 = l12 & 3, r1 = r12 >> 2, r2 = r12 & 3;
      float s01 = 0.f, s23 = 0.f;
#pragma unroll
      for (int d = 0; d < 4; ++d) {
        s01 += peps[PIDX(0, col, (p >> 1), 0, d, l1, r1)] *
               peps[PIDX(1, col, (p & 1), d, d2, l2, r2)];
        s23 += peps[PIDX(2, col, (p >> 1), d2, d, l1, r1)] *
               peps[PIDX(3, col, (p & 1), d, 0, l2, r2)];
      }
      p01[e] = s01;
      p23[e] = s23;
    }
    __syncthreads();
    const int coloffs[3] = {COL1, COL2, COL3};
    float* out = ws + coloffs[col - 1];
#pragma unroll
    for (int k = 0; k < 8; ++k) {
      int eq = part * 8192 + (k * 256 + t) * 4;
      int r34b = eq & 15;
      int r12 = (eq >> 4) & 15, l34 = (eq >> 8) & 15, l12 = (eq >> 12) & 15;
      int p = eq >> 16;
      int pa = p >> 2, pb = p & 3;
      float4 acc = {0.f, 0.f, 0.f, 0.f};
#pragma unroll
      for (int d2 = 0; d2 < 4; ++d2) {
        float a01 = p01[((((pa * 4 + d2) << 4) | l12) << 4) | r12];
        const float4 b4 =
            *(const float4*)&p23[((((pb * 4 + d2) << 4) | l34) << 4) | r34b];
        acc.x += a01 * b4.x;
        acc.y += a01 * b4.y;
        acc.z += a01 * b4.z;
        acc.w += a01 * b4.w;
      }
      *(float4*)&out[eq] = acc;
    }
  } else {
    int col = (bid == 384) ? 0 : 4;
    const int lsh = (col == 0) ? 0 : 2;
    const int rsh = (col == 4) ? 0 : 2;
    const int ldim = 1 << lsh, rdim = 1 << rsh;
    const int LLB = 2 * lsh, RRB = 2 * rsh;
    const int LL = 1 << LLB, RR = 1 << RRB;
    int n12 = (LL * RR) << 4;
    for (int e = t; e < n12; e += 256) {
      int r12 = e & (RR - 1);
      int l12 = (e >> RRB) & (LL - 1);
      int d2 = (e >> (RRB + LLB)) & 3;
      int p = e >> (RRB + LLB + 2);
      int l1 = l12 >> lsh, l2 = l12 & (ldim - 1);
      int r1 = r12 >> rsh, r2 = r12 & (rdim - 1);
      float s01 = 0.f, s23 = 0.f;
      for (int d = 0; d < 4; ++d) {
        s01 += peps[PIDX(0, col, (p >> 1), 0, d, l1, r1)] *
               peps[PIDX(1, col, (p & 1), d, d2, l2, r2)];
        s23 += peps[PIDX(2, col, (p >> 1), d2, d, l1, r1)] *
               peps[PIDX(3, col, (p & 1), d, 0, l2, r2)];
      }
      p01[e] = s01;
      p23[e] = s23;
    }
    __syncthreads();
    const int LB = 2 * LLB, RB = 2 * RRB;
    int total = 16 << (LB + RB);  // 4096
    float* out = ws + ((col == 0) ? COL0 : COL4);
    for (int e = t; e < total; e += 256) {
      int r = e & ((1 << RB) - 1);
      int l = (e >> RB) & ((1 << LB) - 1);
      int p = e >> (RB + LB);
      int r34 = r & (RR - 1), r12 = r >> RRB;
      int l34 = l & (LL - 1), l12 = l >> LLB;
      int pa = p >> 2, pb = p & 3;
      float s = 0.f;
      for (int d2 = 0; d2 < 4; ++d2) {
        s += p01[((((pa * 4 + d2) << LLB) | l12) << RRB) | r12] *
             p23[((((pb * 4 + d2) << LLB) | l34) << RRB) | r34];
      }
      out[e] = s;
    }
  }
}

// ------------------- M01 / M34T (edge-pair contractions) -------------------
__global__ __launch_bounds__(256) void k_small(const float* __restrict__ ws,
                                               float* __restrict__ m01,
                                               float* __restrict__ m34t) {
  __shared__ float c3buf[4112], c4buf[4112];
  int t = threadIdx.x;
  if (blockIdx.x < 64) {
    int c1 = blockIdx.x >> 2, q = blockIdx.x & 3;
    int r2l = t & 63, c0g = t >> 6;  // wave-uniform c0 group (4 c0 each)
    int R2 = q * 64 + r2l;
    const float* col0 = ws + COL0;
    const float* col1 = ws + COL1;
    float a0 = 0.f, a1 = 0.f, a2 = 0.f, a3 = 0.f;
    for (int R1 = 0; R1 < 256; ++R1) {
      float bv = col1[(c1 * 256 + R1) * 256 + R2];  // coalesced
      a0 += col0[(c0g * 4 + 0) * 256 + R1] * bv;    // uniform -> s_load
      a1 += col0[(c0g * 4 + 1) * 256 + R1] * bv;
      a2 += col0[(c0g * 4 + 2) * 256 + R1] * bv;
      a3 += col0[(c0g * 4 + 3) * 256 + R1] * bv;
    }
    m01[((c0g * 4 + 0) * 16 + c1) * 256 + R2] = a0;  // coalesced
    m01[((c0g * 4 + 1) * 16 + c1) * 256 + R2] = a1;
    m01[((c0g * 4 + 2) * 16 + c1) * 256 + R2] = a2;
    m01[((c0g * 4 + 3) * 16 + c1) * 256 + R2] = a3;
  } else {
    int L3 = blockIdx.x - 64;  // 0..255
    const float* col3 = ws + COL3;
    const float* col4 = ws + COL4;
    for (int e = t; e < 4096; e += 256) {
      c4buf[(e >> 8) * 257 + (e & 255)] = col4[e];
      c3buf[(e >> 8) * 257 + (e & 255)] =
          col3[(e >> 8) * 65536 + L3 * 256 + (e & 255)];
    }
    __syncthreads();
    int c3 = t >> 4, c4 = t & 15;
    float acc = 0.f;
    for (int B = 0; B < 256; ++B)
      acc += c3buf[c3 * 257 + B] * c4buf[c4 * 257 + B];
    m34t[L3 * 256 + t] = acc;
  }
}

// ---------------- T012[c2][c01][R3] = M01 x Col2 ---------------------------
__global__ __launch_bounds__(256) void k_t012(const float* __restrict__ m01,
                                              const float* __restrict__ col2,
                                              float* __restrict__ t012) {
  __shared__ float A[4096];  // [i=16][R2=256]
  int t = threadIdx.x;       // R3
  int c2 = blockIdx.x & 15, tg = blockIdx.x >> 4;
#pragma unroll
  for (int k = 0; k < 4; ++k)
    *(float4*)&A[(k * 256 + t) * 4] =
        *(const float4*)&m01[tg * 4096 + (k * 256 + t) * 4];
  __syncthreads();
  float acc[16] = {};
  for (int R2 = 0; R2 < 256; R2 += 4) {
    float b0 = col2[c2 * 65536 + (R2 + 0) * 256 + t];
    float b1 = col2[c2 * 65536 + (R2 + 1) * 256 + t];
    float b2 = col2[c2 * 65536 + (R2 + 2) * 256 + t];
    float b3 = col2[c2 * 65536 + (R2 + 3) * 256 + t];
#pragma unroll
    for (int i = 0; i < 16; ++i) {
      float4 a4 = *(const float4*)&A[i * 256 + R2];  // broadcast b128
      acc[i] += a4.x * b0 + a4.y * b1 + a4.z * b2 + a4.w * b3;
    }
  }
#pragma unroll
  for (int i = 0; i < 16; ++i)
    t012[c2 * 65536 + (tg * 16 + i) * 256 + t] = acc[i];  // coalesced
}

// ---------------- psi = T012 x M34T, emitted in GATE layout ----------------
// Block tg = c01. acc[i=c2][t=c34]. Gate addr = c3<<16|c4<<12|c0<<8|c1<<4|c2.
__global__ __launch_bounds__(256) void k_psi0(const float* __restrict__ t012,
                                              const float* __restrict__ m34t,
                                              float* __restrict__ psi) {
  __shared__ float A[4096];  // [i=c2=16][L3=256]
  __shared__ float S[4112];  // [c2=16][c34=257-padded]
  int t = threadIdx.x;       // c34 (and L3 for staging)
  int tg = blockIdx.x;       // c01
#pragma unroll
  for (int i = 0; i < 16; ++i)
    A[i * 256 + t] = t012[i * 65536 + tg * 256 + t];  // coalesced 1KB chunks
  __syncthreads();
  float acc[16] = {};
  for (int L3 = 0; L3 < 256; L3 += 4) {
    float b0 = m34t[(L3 + 0) * 256 + t];
    float b1 = m34t[(L3 + 1) * 256 + t];
    float b2 = m34t[(L3 + 2) * 256 + t];
    float b3 = m34t[(L3 + 3) * 256 + t];
#pragma unroll
    for (int i = 0; i < 16; ++i) {
      float4 a4 = *(const float4*)&A[i * 256 + L3];  // broadcast b128
      acc[i] += a4.x * b0 + a4.y * b1 + a4.z * b2 + a4.w * b3;
    }
  }
#pragma unroll
  for (int i = 0; i < 16; ++i) S[i * 257 + t] = acc[i];
  __syncthreads();
  // store: u = c3*16 + c2, v = c4 -> 64B runs (c2 lane-consecutive)
  int c3 = t >> 4, c2 = t & 15;
  int base = c3 * 65536 + (tg >> 4) * 256 + (tg & 15) * 16 + c2;
#pragma unroll
  for (int v = 0; v < 16; ++v)
    psi[base + v * 4096] = S[c2 * 257 + c3 * 16 + v];
}

// ---------------- register-level 2-qubit gate ------------------------------
template <int NB, int HI, int LO>
__device__ __forceinline__ void gate2(float* x, const float* __restrict__ g) {
  constexpr int H = 1 << HI, L = 1 << LO, N = 1 << NB;
#pragma unroll
  for (int o = 0; o < N; ++o) {
    if (o & (H | L)) continue;
    float v0 = x[o], v1 = x[o + L], v2 = x[o + H], v3 = x[o + H + L];
    x[o]         = g[0]  * v0 + g[1]  * v1 + g[2]  * v2 + g[3]  * v3;
    x[o + L]     = g[4]  * v0 + g[5]  * v1 + g[6]  * v2 + g[7]  * v3;
    x[o + H]     = g[8]  * v0 + g[9]  * v1 + g[10] * v2 + g[11] * v3;
    x[o + H + L] = g[12] * v0 + g[13] * v1 + g[14] * v2 + g[15] * v3;
  }
}

// V column transform: 4-bit nibble, x bit3 = row 0; bonds (3,2),(2,1),(1,0)
template <int ST>
__device__ __forceinline__ void vxf(float* s, const float* __restrict__ g, int b) {
  float x[16];
#pragma unroll
  for (int m = 0; m < 16; ++m) x[m] = s[PAD(b + m * ST)];
  gate2<4, 3, 2>(x, g);
  gate2<4, 2, 1>(x, g);
  gate2<4, 1, 0>(x, g);
#pragma unroll
  for (int m = 0; m < 16; ++m) s[PAD(b + m * ST)] = x[m];
}

// Bond-pair round (512 threads, 1 group each): gate on (B2,B1) then (B1,B0).
template <int B2, int B1, int B0>
__device__ __forceinline__ void bondpair(float* s, const float* __restrict__ g,
                                         int t) {
  constexpr int MASK = (1 << B2) | (1 << B1) | (1 << B0);
  int b = 0, rem = t;
#pragma unroll
  for (int p = 0; p < 12; ++p) {
    if (!((MASK >> p) & 1)) {
      b |= (rem & 1) << p;
      rem >>= 1;
    }
  }
  float x[8];
#pragma unroll
  for (int m = 0; m < 8; ++m) {
    int off = ((m >> 2) & 1) * (1 << B2) + ((m >> 1) & 1) * (1 << B1) +
              (m & 1) * (1 << B0);
    x[m] = s[PAD(b + off)];
  }
  gate2<3, 2, 1>(x, g);  // bond (B2, B1)
  gate2<3, 1, 0>(x, g);  // bond (B1, B0)
#pragma unroll
  for (int m = 0; m < 8; ++m) {
    int off = ((m >> 2) & 1) * (1 << B2) + ((m >> 1) & 1) * (1 << B1) +
              (m & 1) * (1 << B0);
    s[PAD(b + off)] = x[m];
  }
}

// Phase P1: G2_01, G2_12, M16_0, M16_1.
// slab local: c0 = bits 11..8, c1 = 7..4, c2 = 3..0; outer o = (c3,c4).
__global__ __launch_bounds__(512) void k_P1(float* __restrict__ psi,
                                            const float* __restrict__ gate) {
  __shared__ float s[5120];
  float g[16];
#pragma unroll
  for (int i = 0; i < 16; ++i) g[i] = gate[i];
  int t = threadIdx.x;  // 512
  int o = blockIdx.x;
#pragma unroll
  for (int i = 0; i < 2; ++i) {
    int f = (i * 512 + t) * 4;
    *(float4*)(s + PAD(f)) = *(const float4*)(psi + o * 4096 + f);
  }
  __syncthreads();
  // G2_01 + G2_12, row r: bits (8+q, 4+q, q), q = 3-r
  bondpair<8, 4, 0>(s, g, t);
  __syncthreads();
  bondpair<9, 5, 1>(s, g, t);
  __syncthreads();
  bondpair<10, 6, 2>(s, g, t);
  __syncthreads();
  bondpair<11, 7, 3>(s, g, t);
  __syncthreads();
  if (t < 256) vxf<256>(s, g, t);                           // M16_0 (bits 11..8)
  __syncthreads();
  if (t < 256) vxf<16>(s, g, ((t >> 4) << 8) | (t & 15));   // M16_1 (bits 7..4)
  __syncthreads();
#pragma unroll
  for (int i = 0; i < 2; ++i) {
    int f = (i * 512 + t) * 4;
    *(float4*)(psi + o * 4096 + f) = *(const float4*)(s + PAD(f));
  }
}

// Phase P2: G2_23, G2_34, M16_2, M16_3, M16_4.
// slab local: c3 = bits 11..8, c4 = 7..4, c2 = 3..0; outer o = (c0,c1).
// LAST: gather into out, skip psi writeback.
template <bool LAST>
__global__ __launch_bounds__(512) void k_P2(float* __restrict__ psi,
                                            const float* __restrict__ gate,
                                            const int* __restrict__ x,
                                            float* __restrict__ out) {
  __shared__ float s[5120];
  float g[16];
#pragma unroll
  for (int i = 0; i < 16; ++i) g[i] = gate[i];
  int t = threadIdx.x;  // 512
  int o = blockIdx.x;
#pragma unroll
  for (int i = 0; i < 2; ++i) {
    int f = (i * 512 + t) * 4;
    int addr = (f >> 8) * 65536 + ((f >> 4) & 15) * 4096 + o * 16 + (f & 15);
    *(float4*)(s + PAD(f)) = *(const float4*)(psi + addr);
  }
  __syncthreads();
  // G2_23 + G2_34, row r: bits (q, 8+q, 4+q), q = 3-r
  bondpair<0, 8, 4>(s, g, t);
  __syncthreads();
  bondpair<1, 9, 5>(s, g, t);
  __syncthreads();
  bondpair<2, 10, 6>(s, g, t);
  __syncthreads();
  bondpair<3, 11, 7>(s, g, t);
  __syncthreads();
  if (t < 256) vxf<1>(s, g, t * 16);                        // M16_2 (bits 3..0)
  __syncthreads();
  if (t < 256) vxf<256>(s, g, t);                           // M16_3 (bits 11..8)
  __syncthreads();
  if (t < 256) vxf<16>(s, g, ((t >> 4) << 8) | (t & 15));   // M16_4 (bits 7..4)
  __syncthreads();
  if (LAST) {
    if (t < 64) {
      int idx = 0;
#pragma unroll
      for (int q = 0; q < 20; ++q) {
        int i = q / 5, j = q % 5;
        int pos = (j == 0) ? (11 - i)
                 : (j == 1) ? (7 - i)
                 : (j == 2) ? (3 - i)
                 : (j == 3) ? (19 - i)
                            : (15 - i);
        idx |= x[t * 20 + q] << pos;
      }
      if (((idx >> 4) & 255) == o) {
        int local = ((idx >> 16) & 15) * 256 + ((idx >> 12) & 15) * 16 +
                    (idx & 15);
        out[t] = s[PAD(local)];
      }
    }
  } else {
#pragma unroll
    for (int i = 0; i < 2; ++i) {
      int f = (i * 512 + t) * 4;
      int addr = (f >> 8) * 65536 + ((f >> 4) & 15) * 4096 + o * 16 + (f & 15);
      *(float4*)(psi + addr) = *(const float4*)(s + PAD(f));
    }
  }
}

// ---------------------------------------------------------------------------
extern "C" void kernel_launch(void* const* d_in, const int* in_sizes, int n_in,
                              void* d_out, int out_size, void* d_ws, size_t ws_size,
                              hipStream_t stream) {
  const int* x = (const int*)d_in[0];
  const float* peps = (const float*)d_in[1];
  const float* gate = (const float*)d_in[2];
  float* ws = (float*)d_ws;
  float* psi = ws + PSIO;  // gate layout from k_psi0 onward
  float* out = (float*)d_out;

  k_build_cols<<<386, 256, 0, stream>>>(peps, ws);
  k_small<<<320, 256, 0, stream>>>(ws, ws + M01TO, ws + M34TO);
  k_t012<<<256, 256, 0, stream>>>(ws + M01TO, ws + COL2, ws + T12TO);
  k_psi0<<<256, 256, 0, stream>>>(ws + T12TO, ws + M34TO, psi);

  for (int it = 0; it < 5; ++it) {
    k_P1<<<256, 512, 0, stream>>>(psi, gate);
    if (it < 4)
      k_P2<false><<<256, 512, 0, stream>>>(psi, gate, x, out);
    else
      k_P2<true><<<256, 512, 0, stream>>>(psi, gate, x, out);
  }
}